// Round 4
// baseline (516.037 us; speedup 1.0000x reference)
//
#include <hip/hip_runtime.h>
#include <hip/hip_fp16.h>

// SparseEncoder4D: gather-GEMM-scatter sparse conv (1->8->8->1) + dense scatter.
// R4 (= R3 with compile fix): nontemporal store needs a native clang vector
// type, not HIP_vector_type. Theory:
// (a) layer1 exploits feats==ones -> no gather, single streaming pass over mask;
// (b) k_h2p marks idx/mask streams + part stores NONTEMPORAL so they stop
//     evicting the 2.4 MB fp16 h1 table from the 4 MiB/XCD L2 (R2 counter
//     evidence: FETCH 690 MB = stream-thrashed gathers);
// (c) gathers predicated on mask!=0 (Bernoulli 1/2) -> half the VMEM requests.

#define KK 81
#define CH 8
#define KC 27   // k per y-chunk (layer 2 split)
#define NY 3
#define BB 2
#define TT 4
#define ZZ 32
#define YY 256
#define XX 256

typedef __attribute__((ext_vector_type(8))) _Float16 half8;  // 16 B
typedef __attribute__((ext_vector_type(4))) float f32x4;     // native vec for nt-store

__global__ __launch_bounds__(256) void k_zero(float4* __restrict__ out, int n4) {
    int i = blockIdx.x * blockDim.x + threadIdx.x;
    if (i < n4) out[i] = make_float4(0.f, 0.f, 0.f, 0.f);
}

// Fused layer 1 (feats == ones): h1[n,c] = relu( sum_k mask[n,k] * w1[k,0,c] )
// Pure stream over mask; w1 rows are wave-uniform (s_load).
__global__ __launch_bounds__(256) void k_h1f(const float* __restrict__ w1,
                                             const int* __restrict__ nbr_mask,
                                             half8* __restrict__ h1, int n_total) {
    int n = blockIdx.x * blockDim.x + threadIdx.x;
    if (n >= n_total) return;
    const int* mp = nbr_mask + (long)n * KK;
    float acc[CH];
#pragma unroll
    for (int c = 0; c < CH; c++) acc[c] = 0.f;
#pragma unroll 9
    for (int k = 0; k < KK; k++) {
        float fm = (float)mp[k];           // per-lane row is 6 cachelines; L1-reused over k
#pragma unroll
        for (int c = 0; c < CH; c++) acc[c] += fm * w1[k * CH + c];
    }
    half8 r;
#pragma unroll
    for (int c = 0; c < CH; c++) r[c] = (_Float16)fmaxf(acc[c], 0.f);
    h1[n] = r;
}

// Layer 2 partial: part[y][n][d] = sum_{k in chunk y, c} m*h1[nbr][c]*w2[k,c,d]
__global__ __launch_bounds__(256) void k_h2p(const half8* __restrict__ h1,
                                             const float* __restrict__ w2,
                                             const int* __restrict__ nbr_idx,
                                             const int* __restrict__ nbr_mask,
                                             float* __restrict__ part, int n_total) {
    int n = blockIdx.x * blockDim.x + threadIdx.x;
    int y = blockIdx.y;
    if (n >= n_total) return;
    const int* ip = nbr_idx + (long)n * KK + y * KC;
    const int* mp = nbr_mask + (long)n * KK + y * KC;
    float acc[CH];
#pragma unroll
    for (int c = 0; c < CH; c++) acc[c] = 0.f;
#pragma unroll 9
    for (int k = 0; k < KC; k++) {
        int m  = __builtin_nontemporal_load(&mp[k]);   // stream: don't pollute L2
        int ix = __builtin_nontemporal_load(&ip[k]);   // stream: don't pollute L2
        if (m != 0) {                                  // exec-masked: half the gathers
            half8 hv = h1[ix];                         // 16B gather, 2.4 MB L2-resident table
            const float* wk = w2 + ((long)(y * KC + k)) * CH * CH;  // wave-uniform
#pragma unroll
            for (int d = 0; d < CH; d++) {
                acc[d] += (float)hv[0] * wk[0 * CH + d] + (float)hv[1] * wk[1 * CH + d] +
                          (float)hv[2] * wk[2 * CH + d] + (float)hv[3] * wk[3 * CH + d] +
                          (float)hv[4] * wk[4 * CH + d] + (float)hv[5] * wk[5 * CH + d] +
                          (float)hv[6] * wk[6 * CH + d] + (float)hv[7] * wk[7 * CH + d];
            }
        }
    }
    float* o = part + ((long)y * n_total + n) * CH;
    f32x4 r0 = {acc[0], acc[1], acc[2], acc[3]};
    f32x4 r1 = {acc[4], acc[5], acc[6], acc[7]};
    __builtin_nontemporal_store(r0, (f32x4*)o);        // part is write-once stream
    __builtin_nontemporal_store(r1, (f32x4*)(o + 4));
}

// Sum 3 partials, relu, dot with w_out -> outf[n]
__global__ __launch_bounds__(256) void k_fin(const float* __restrict__ part,
                                             const float* __restrict__ w_out,
                                             float* __restrict__ outf, int n_total) {
    int n = blockIdx.x * blockDim.x + threadIdx.x;
    if (n >= n_total) return;
    const float4* p0 = (const float4*)(part + (long)n * CH);
    const float4* p1 = (const float4*)(part + ((long)n_total + n) * CH);
    const float4* p2 = (const float4*)(part + ((long)2 * n_total + n) * CH);
    float4 a0 = p0[0], a1 = p0[1], b0 = p1[0], b1 = p1[1], c0 = p2[0], c1 = p2[1];
    float s[CH];
    s[0] = a0.x + b0.x + c0.x; s[1] = a0.y + b0.y + c0.y;
    s[2] = a0.z + b0.z + c0.z; s[3] = a0.w + b0.w + c0.w;
    s[4] = a1.x + b1.x + c1.x; s[5] = a1.y + b1.y + c1.y;
    s[6] = a1.z + b1.z + c1.z; s[7] = a1.w + b1.w + c1.w;
    float o = 0.f;
#pragma unroll
    for (int c = 0; c < CH; c++) o += fmaxf(s[c], 0.f) * w_out[c];
    outf[n] = o;
}

__device__ __forceinline__ int cell_of(const int* coords, const int* batch, int n) {
    int4 c = *(const int4*)(coords + 4 * n);  // (x, y, z, t)
    int b = batch[n];
    return (((b * TT + c.w) * ZZ + c.z) * YY + c.y) * XX + c.x;
}

// Deterministic last-write-wins scatter: winner = max n (numpy index order).
__global__ __launch_bounds__(256) void k_scat_max(const int* __restrict__ coords,
                                                  const int* __restrict__ batch,
                                                  int* __restrict__ dsti, int n_total) {
    int n = blockIdx.x * blockDim.x + threadIdx.x;
    if (n >= n_total) return;
    atomicMax(dsti + cell_of(coords, batch, n), n + 1);
}

__global__ __launch_bounds__(256) void k_scat_write(const int* __restrict__ coords,
                                                    const int* __restrict__ batch,
                                                    const float* __restrict__ outf,
                                                    int* __restrict__ dsti,
                                                    float* __restrict__ dstf, int n_total) {
    int n = blockIdx.x * blockDim.x + threadIdx.x;
    if (n >= n_total) return;
    int cell = cell_of(coords, batch, n);
    if (dsti[cell] == n + 1) dstf[cell] = outf[n];
}

extern "C" void kernel_launch(void* const* d_in, const int* in_sizes, int n_in,
                              void* d_out, int out_size, void* d_ws, size_t ws_size,
                              hipStream_t stream) {
    const float* w1       = (const float*)d_in[1];
    const float* w2       = (const float*)d_in[2];
    const float* w_out    = (const float*)d_in[3];
    const int*   nbr_idx  = (const int*)d_in[4];
    const int*   nbr_mask = (const int*)d_in[5];
    const int*   coords   = (const int*)d_in[6];
    const int*   batch    = (const int*)d_in[7];

    int n_total = in_sizes[0];
    // ws: h1 fp16 table (2.4 MB) | part fp32 (3*N*8 = 14.4 MB) | outf (0.6 MB)
    half8* h1   = (half8*)d_ws;
    float* part = (float*)((char*)d_ws + (size_t)n_total * sizeof(half8));
    float* outf = part + (size_t)NY * n_total * CH;
    float* out  = (float*)d_out;

    int n4 = out_size / 4;
    k_zero<<<(n4 + 255) / 256, 256, 0, stream>>>((float4*)out, n4);

    int nb = (n_total + 255) / 256;
    k_h1f<<<nb, 256, 0, stream>>>(w1, nbr_mask, h1, n_total);
    dim3 gsplit(nb, NY);
    k_h2p<<<gsplit, 256, 0, stream>>>(h1, w2, nbr_idx, nbr_mask, part, n_total);
    k_fin<<<nb, 256, 0, stream>>>(part, w_out, outf, n_total);
    k_scat_max<<<nb, 256, 0, stream>>>(coords, batch, (int*)out, n_total);
    k_scat_write<<<nb, 256, 0, stream>>>(coords, batch, outf, (int*)out, out, n_total);
}

// Round 5
// 342.837 us; speedup vs baseline: 1.5052x; 1.5052x over previous
//
#include <hip/hip_runtime.h>
#include <hip/hip_fp16.h>

// SparseEncoder4D: gather-GEMM-scatter sparse conv (1->8->8->1) + dense scatter.
// R5: idx-range multi-pass gather. R2/R4 counters showed the 2.4 MB fp16 h1
// table thrashes out of the 4 MiB/XCD L2 (~48 B HBM fill per 16 B gather,
// 690 MB FETCH) because ~25k stream fills land between table-line reuses.
// Fix: NP=2 passes, pass p gathers only idx in [p*slice,(p+1)*slice) from a
// 1.2 MB slice that stays L2-resident; idx re-streamed per pass from L3.
// Masked-out / out-of-range lanes gather a dedicated zero row (h1[N]) ->
// branch-free straight-line body, k's processed in pairs for MLP.
// Mask is pre-packed to 81-bit bitmask by k_h1b (feats==ones -> layer1 needs
// only mask), so k_h2f streams 50.4 MB/pass instead of 97 MB.

#define KK 81
#define CH 8
#define NP 2     // idx-range passes; slice = ceil(N/NP)
#define TT 4
#define ZZ 32
#define YY 256
#define XX 256

typedef __attribute__((ext_vector_type(8))) _Float16 half8;  // 16 B

// Layer 1 (feats == ones): h1[n,c] = relu(sum_k mask*w1[k,0,c]); also pack
// mask bits (3 words/n) and write the zero dummy row at h1[N].
__global__ __launch_bounds__(256) void k_h1b(const float* __restrict__ w1,
                                             const int* __restrict__ nbr_mask,
                                             half8* __restrict__ h1,
                                             unsigned* __restrict__ bits, int n_total) {
    int n = blockIdx.x * blockDim.x + threadIdx.x;
    if (n == 0) {  // zero row used as gather target for inactive lanes
        half8 z;
#pragma unroll
        for (int c = 0; c < CH; c++) z[c] = (_Float16)0.f;
        h1[n_total] = z;
    }
    if (n >= n_total) return;
    const int* mp = nbr_mask + (long)n * KK;
    float acc[CH] = {0.f, 0.f, 0.f, 0.f, 0.f, 0.f, 0.f, 0.f};
    unsigned b0 = 0, b1 = 0, b2 = 0;
#pragma unroll
    for (int k = 0; k < KK; k++) {      // full unroll: bit-word index static
        int m = mp[k];
        if (k < 32)      b0 |= (unsigned)(m & 1) << k;
        else if (k < 64) b1 |= (unsigned)(m & 1) << (k - 32);
        else             b2 |= (unsigned)(m & 1) << (k - 64);
        float fm = (float)m;
#pragma unroll
        for (int c = 0; c < CH; c++) acc[c] += fm * w1[k * CH + c];
    }
    half8 r;
#pragma unroll
    for (int c = 0; c < CH; c++) r[c] = (_Float16)fmaxf(acc[c], 0.f);
    h1[n] = r;
    bits[3 * n + 0] = b0;
    bits[3 * n + 1] = b1;
    bits[3 * n + 2] = b2;
}

__device__ __forceinline__ void fma_block(float acc[CH], half8 hv, const float* wk) {
    // wk wave-uniform (k from uniform loop counters) -> s_load + SGPR FMA operand
#pragma unroll
    for (int d = 0; d < CH; d++)
        acc[d] += (float)hv[0] * wk[0 * CH + d] + (float)hv[1] * wk[1 * CH + d] +
                  (float)hv[2] * wk[2 * CH + d] + (float)hv[3] * wk[3 * CH + d] +
                  (float)hv[4] * wk[4 * CH + d] + (float)hv[5] * wk[5 * CH + d] +
                  (float)hv[6] * wk[6 * CH + d] + (float)hv[7] * wk[7 * CH + d];
}

// Layer 2 + head, NP idx-range passes. out[n] = sum_d relu(acc[d])*w_out[d].
__global__ __launch_bounds__(256) void k_h2f(const half8* __restrict__ h1,
                                             const float* __restrict__ w2,
                                             const int* __restrict__ nbr_idx,
                                             const unsigned* __restrict__ bits,
                                             const float* __restrict__ w_out,
                                             float* __restrict__ outf,
                                             int n_total, int slice) {
    int n = blockIdx.x * blockDim.x + threadIdx.x;
    if (n >= n_total) return;
    const int* ip = nbr_idx + (long)n * KK;
    unsigned bw0 = bits[3 * n + 0], bw1 = bits[3 * n + 1], bw2 = bits[3 * n + 2];
    int dummy = n_total;            // zero row: inactive lanes gather here (hot line)
    float acc[CH] = {0.f, 0.f, 0.f, 0.f, 0.f, 0.f, 0.f, 0.f};
    unsigned uslice = (unsigned)slice;

    for (int p = 0; p < NP; p++) {
        unsigned lo = (unsigned)(p * slice);
        // words 0,1: 32 k's each as 16 pairs (j, j+16) — 2 gathers in flight
#pragma unroll
        for (int w = 0; w < 2; w++) {
            unsigned B = w ? bw1 : bw0;
            for (int j = 0; j < 16; j++) {
                int kA = w * 32 + j, kB = kA + 16;
                unsigned bA = (B >> j) & 1u, bB = (B >> (j + 16)) & 1u;
                int ixA = ip[kA], ixB = ip[kB];
                bool okA = bA && ((unsigned)ixA - lo) < uslice;
                bool okB = bB && ((unsigned)ixB - lo) < uslice;
                half8 hA = h1[okA ? ixA : dummy];
                half8 hB = h1[okB ? ixB : dummy];
                fma_block(acc, hA, w2 + kA * CH * CH);
                fma_block(acc, hB, w2 + kB * CH * CH);
            }
        }
        // word 2: k=64..79 as 8 pairs (j, j+8), then tail k=80 (bit 16)
        for (int j = 0; j < 8; j++) {
            int kA = 64 + j, kB = kA + 8;
            unsigned bA = (bw2 >> j) & 1u, bB = (bw2 >> (j + 8)) & 1u;
            int ixA = ip[kA], ixB = ip[kB];
            bool okA = bA && ((unsigned)ixA - lo) < uslice;
            bool okB = bB && ((unsigned)ixB - lo) < uslice;
            half8 hA = h1[okA ? ixA : dummy];
            half8 hB = h1[okB ? ixB : dummy];
            fma_block(acc, hA, w2 + kA * CH * CH);
            fma_block(acc, hB, w2 + kB * CH * CH);
        }
        {
            int ixT = ip[80];
            bool okT = ((bw2 >> 16) & 1u) && ((unsigned)ixT - lo) < uslice;
            half8 hT = h1[okT ? ixT : dummy];
            fma_block(acc, hT, w2 + 80 * CH * CH);
        }
    }
    float o = 0.f;
#pragma unroll
    for (int c = 0; c < CH; c++) o += fmaxf(acc[c], 0.f) * w_out[c];
    outf[n] = o;
}

__device__ __forceinline__ int cell_of(const int* coords, const int* batch, int n) {
    int4 c = *(const int4*)(coords + 4 * n);  // (x, y, z, t), 16B-aligned rows
    int b = batch[n];
    return (((b * TT + c.w) * ZZ + c.z) * YY + c.y) * XX + c.x;
}

// Deterministic last-write-wins scatter: winner = max n (numpy index order).
__global__ __launch_bounds__(256) void k_scat_max(const int* __restrict__ coords,
                                                  const int* __restrict__ batch,
                                                  int* __restrict__ dsti, int n_total) {
    int n = blockIdx.x * blockDim.x + threadIdx.x;
    if (n >= n_total) return;
    atomicMax(dsti + cell_of(coords, batch, n), n + 1);
}

// No __restrict__ on the aliased int/float views of d_out.
__global__ __launch_bounds__(256) void k_scat_write(const int* __restrict__ coords,
                                                    const int* __restrict__ batch,
                                                    const float* __restrict__ outf,
                                                    int* dsti, float* dstf, int n_total) {
    int n = blockIdx.x * blockDim.x + threadIdx.x;
    if (n >= n_total) return;
    int cell = cell_of(coords, batch, n);
    if (dsti[cell] == n + 1) dstf[cell] = outf[n];
}

extern "C" void kernel_launch(void* const* d_in, const int* in_sizes, int n_in,
                              void* d_out, int out_size, void* d_ws, size_t ws_size,
                              hipStream_t stream) {
    const float* w1       = (const float*)d_in[1];
    const float* w2       = (const float*)d_in[2];
    const float* w_out    = (const float*)d_in[3];
    const int*   nbr_idx  = (const int*)d_in[4];
    const int*   nbr_mask = (const int*)d_in[5];
    const int*   coords   = (const int*)d_in[6];
    const int*   batch    = (const int*)d_in[7];

    int n_total = in_sizes[0];
    int slice = (n_total + NP - 1) / NP;

    // ws: h1 fp16 table (N+1 rows, 2.4 MB) | bits (3N uints, 1.8 MB) | outf (0.6 MB)
    half8*    h1   = (half8*)d_ws;
    unsigned* bits = (unsigned*)((char*)d_ws + (size_t)(n_total + 1) * sizeof(half8));
    float*    outf = (float*)((char*)bits + (size_t)3 * n_total * sizeof(unsigned));
    float*    out  = (float*)d_out;

    hipMemsetAsync(out, 0, (size_t)out_size * sizeof(float), stream);

    int nb = (n_total + 255) / 256;
    k_h1b<<<nb, 256, 0, stream>>>(w1, nbr_mask, h1, bits, n_total);
    k_h2f<<<nb, 256, 0, stream>>>(h1, w2, nbr_idx, bits, w_out, outf, n_total, slice);
    k_scat_max<<<nb, 256, 0, stream>>>(coords, batch, (int*)out, n_total);
    k_scat_write<<<nb, 256, 0, stream>>>(coords, batch, outf, (int*)out, out, n_total);
}

// Round 6
// 331.332 us; speedup vs baseline: 1.5575x; 1.0347x over previous
//
#include <hip/hip_runtime.h>
#include <hip/hip_fp16.h>

// SparseEncoder4D: gather-GEMM-scatter sparse conv (1->8->8->1) + dense scatter.
// R6: R5 counters showed k_h2f TA/latency-bound: 22% occupancy (no k-split) and
// 64-distinct-lines-per-wave uncoalesced idx/mask loads (lane stride 324 B).
// Fix: (a) all [n][k] row streams staged block-wise through LDS with flat
// coalesced global loads (256 rows x 27 k = 27.6 KB tiles; LDS read bank
// stride 27 -> <=2-way, free); (b) NY=3 k-split restored (5 blocks/CU by LDS,
// 20 waves/CU) with fp32 partials + k_fin; (c) NP=2 idx-range passes kept so
// gathers hit a 1.2 MB L2-resident half-table slice; masked / out-of-slice
// lanes gather a hot zero row (branch-free). Mask consumed once (feats==ones)
// and carried as transposed bitmask bitsT[3][N] (coalesced).

#define KK 81
#define CH 8
#define KC 27    // k per y-chunk
#define NY 3
#define NP 2     // idx-range passes; slice = ceil(N/NP)
#define TT 4
#define ZZ 32
#define YY 256
#define XX 256

typedef __attribute__((ext_vector_type(8))) _Float16 half8;  // 16 B

// ---------------- layer 1 (feats == ones): h1 + transposed bitmask ----------
__global__ __launch_bounds__(256) void k_h1b(const float* __restrict__ w1,
                                             const int* __restrict__ nbr_mask,
                                             half8* __restrict__ h1,
                                             unsigned* __restrict__ bitsT, int n_total) {
    __shared__ int lm[256 * KC];  // 27.6 KB
    const int tid = threadIdx.x;
    const int n0 = blockIdx.x * 256;
    const int n = n0 + tid;

    if (blockIdx.x == 0 && tid == 0) {  // zero row: gather target for dead lanes
        half8 z;
#pragma unroll
        for (int c = 0; c < CH; c++) z[c] = (_Float16)0.f;
        h1[n_total] = z;
    }

    float acc[CH] = {0.f, 0.f, 0.f, 0.f, 0.f, 0.f, 0.f, 0.f};
    unsigned cb[3];
#pragma unroll
    for (int ch = 0; ch < 3; ch++) {
        // stage chunk: flat coalesced (consecutive tid -> consecutive addresses
        // within 108 B row-runs; ~6 lines/wave-load vs 64 uncoalesced)
#pragma unroll
        for (int j = 0; j < KC; j++) {
            int i = tid + j * 256;
            int r = i / KC, c = i - r * KC;
            int srcn = n0 + r; if (srcn >= n_total) srcn = n_total - 1;
            lm[i] = nbr_mask[(long)srcn * KK + ch * KC + c];
        }
        __syncthreads();
        unsigned cbits = 0;
        const int* row = lm + tid * KC;   // bank stride 27 -> <=2-way, free
#pragma unroll
        for (int kk = 0; kk < KC; kk++) {
            int m = row[kk];
            cbits |= (unsigned)(m & 1) << kk;
            float fm = (float)m;
            const float* wp = w1 + (ch * KC + kk) * CH;  // wave-uniform s_load
#pragma unroll
            for (int c = 0; c < CH; c++) acc[c] += fm * wp[c];
        }
        cb[ch] = cbits;
        __syncthreads();  // before next chunk overwrites lm
    }

    if (n < n_total) {
        half8 r;
#pragma unroll
        for (int c = 0; c < CH; c++) r[c] = (_Float16)fmaxf(acc[c], 0.f);
        h1[n] = r;
        // pack 3x27 chunk bits into 81-bit little-endian words
        bitsT[n]                = cb[0] | (cb[1] << 27);
        bitsT[n_total + n]      = (cb[1] >> 5) | (cb[2] << 22);
        bitsT[2 * n_total + n]  = cb[2] >> 10;
    }
}

// ---------------- layer 2 partial over one 27-k chunk, NP slice passes ------
__device__ __forceinline__ void fma_block(float acc[CH], half8 hv, const float* wk) {
    // wk wave-uniform -> s_load + SGPR FMA operand
#pragma unroll
    for (int d = 0; d < CH; d++)
        acc[d] += (float)hv[0] * wk[0 * CH + d] + (float)hv[1] * wk[1 * CH + d] +
                  (float)hv[2] * wk[2 * CH + d] + (float)hv[3] * wk[3 * CH + d] +
                  (float)hv[4] * wk[4 * CH + d] + (float)hv[5] * wk[5 * CH + d] +
                  (float)hv[6] * wk[6 * CH + d] + (float)hv[7] * wk[7 * CH + d];
}

__global__ __launch_bounds__(256) void k_h2p3(const half8* __restrict__ h1,
                                              const float* __restrict__ w2,
                                              const int* __restrict__ nbr_idx,
                                              const unsigned* __restrict__ bitsT,
                                              float* __restrict__ part,
                                              int n_total, int slice) {
    __shared__ int lidx[256 * KC];  // 27.6 KB -> 5 blocks/CU, 20 waves/CU
    const int tid = threadIdx.x;
    const int n0 = blockIdx.x * 256;
    const int n = n0 + tid;
    const int y = blockIdx.y;
    const int k0 = y * KC;

    // stage this block's 27-k idx slab (coalesced flat mapping)
#pragma unroll
    for (int j = 0; j < KC; j++) {
        int i = tid + j * 256;
        int r = i / KC, c = i - r * KC;
        int srcn = n0 + r; if (srcn >= n_total) srcn = n_total - 1;
        lidx[i] = nbr_idx[(long)srcn * KK + k0 + c];
    }
    __syncthreads();
    if (n >= n_total) return;

    // this chunk's 27 mask bits (coalesced bitsT loads, wave-uniform select by y)
    unsigned bw0 = bitsT[n], bw1 = bitsT[n_total + n], bw2 = bitsT[2 * n_total + n];
    unsigned mybits;
    if (y == 0)      mybits = bw0;
    else if (y == 1) mybits = (bw0 >> 27) | (bw1 << 5);
    else             mybits = (bw1 >> 22) | (bw2 << 10);

    const int dummy = n_total;        // zero row (hot line)
    const unsigned uslice = (unsigned)slice;
    const int* row = lidx + tid * KC;
    float acc[CH] = {0.f, 0.f, 0.f, 0.f, 0.f, 0.f, 0.f, 0.f};

    for (int p = 0; p < NP; p++) {
        unsigned lo = (unsigned)(p * slice);
#pragma unroll
        for (int kk = 0; kk < KC; kk++) {
            int ix = row[kk];
            bool ok = ((mybits >> kk) & 1u) && ((unsigned)ix - lo) < uslice;
            half8 hv = h1[ok ? ix : dummy];   // 16B gather, 1.2 MB L2-resident slice
            fma_block(acc, hv, w2 + (k0 + kk) * CH * CH);
        }
    }
    float4* o = (float4*)(part + ((long)y * n_total + n) * CH);
    o[0] = make_float4(acc[0], acc[1], acc[2], acc[3]);
    o[1] = make_float4(acc[4], acc[5], acc[6], acc[7]);
}

// ---------------- sum 3 partials, relu, dot w_out ---------------------------
__global__ __launch_bounds__(256) void k_fin(const float* __restrict__ part,
                                             const float* __restrict__ w_out,
                                             float* __restrict__ outf, int n_total) {
    int n = blockIdx.x * blockDim.x + threadIdx.x;
    if (n >= n_total) return;
    const float4* p0 = (const float4*)(part + (long)n * CH);
    const float4* p1 = (const float4*)(part + ((long)n_total + n) * CH);
    const float4* p2 = (const float4*)(part + ((long)2 * n_total + n) * CH);
    float4 a0 = p0[0], a1 = p0[1], b0 = p1[0], b1 = p1[1], c0 = p2[0], c1 = p2[1];
    float s[CH];
    s[0] = a0.x + b0.x + c0.x; s[1] = a0.y + b0.y + c0.y;
    s[2] = a0.z + b0.z + c0.z; s[3] = a0.w + b0.w + c0.w;
    s[4] = a1.x + b1.x + c1.x; s[5] = a1.y + b1.y + c1.y;
    s[6] = a1.z + b1.z + c1.z; s[7] = a1.w + b1.w + c1.w;
    float o = 0.f;
#pragma unroll
    for (int c = 0; c < CH; c++) o += fmaxf(s[c], 0.f) * w_out[c];
    outf[n] = o;
}

// ---------------- deterministic dense scatter -------------------------------
__device__ __forceinline__ int cell_of(const int* coords, const int* batch, int n) {
    int4 c = *(const int4*)(coords + 4 * n);  // (x, y, z, t)
    int b = batch[n];
    return (((b * TT + c.w) * ZZ + c.z) * YY + c.y) * XX + c.x;
}

__global__ __launch_bounds__(256) void k_scat_max(const int* __restrict__ coords,
                                                  const int* __restrict__ batch,
                                                  int* __restrict__ dsti, int n_total) {
    int n = blockIdx.x * blockDim.x + threadIdx.x;
    if (n >= n_total) return;
    atomicMax(dsti + cell_of(coords, batch, n), n + 1);  // winner = max n
}

__global__ __launch_bounds__(256) void k_scat_write(const int* __restrict__ coords,
                                                    const int* __restrict__ batch,
                                                    const float* __restrict__ outf,
                                                    int* dsti, float* dstf, int n_total) {
    int n = blockIdx.x * blockDim.x + threadIdx.x;
    if (n >= n_total) return;
    int cell = cell_of(coords, batch, n);
    if (dsti[cell] == n + 1) dstf[cell] = outf[n];
}

extern "C" void kernel_launch(void* const* d_in, const int* in_sizes, int n_in,
                              void* d_out, int out_size, void* d_ws, size_t ws_size,
                              hipStream_t stream) {
    const float* w1       = (const float*)d_in[1];
    const float* w2       = (const float*)d_in[2];
    const float* w_out    = (const float*)d_in[3];
    const int*   nbr_idx  = (const int*)d_in[4];
    const int*   nbr_mask = (const int*)d_in[5];
    const int*   coords   = (const int*)d_in[6];
    const int*   batch    = (const int*)d_in[7];

    int n_total = in_sizes[0];
    int slice = (n_total + NP - 1) / NP;

    // ws: h1 (N+1 rows fp16, 2.4 MB) | bitsT (3N u32, 1.8 MB) | part (3N*8 f32,
    // 14.4 MB) | outf (0.6 MB)
    half8*    h1   = (half8*)d_ws;
    unsigned* bitsT = (unsigned*)((char*)d_ws + (size_t)(n_total + 1) * sizeof(half8));
    float*    part = (float*)((char*)bitsT + (size_t)3 * n_total * sizeof(unsigned));
    float*    outf = part + (size_t)NY * n_total * CH;
    float*    out  = (float*)d_out;

    hipMemsetAsync(out, 0, (size_t)out_size * sizeof(float), stream);

    int nb = (n_total + 255) / 256;
    k_h1b<<<nb, 256, 0, stream>>>(w1, nbr_mask, h1, bitsT, n_total);
    dim3 g2(nb, NY);
    k_h2p3<<<g2, 256, 0, stream>>>(h1, w2, nbr_idx, bitsT, part, n_total, slice);
    k_fin<<<nb, 256, 0, stream>>>(part, w_out, outf, n_total);
    k_scat_max<<<nb, 256, 0, stream>>>(coords, batch, (int*)out, n_total);
    k_scat_write<<<nb, 256, 0, stream>>>(coords, batch, outf, (int*)out, out, n_total);
}

// Round 7
// 230.248 us; speedup vs baseline: 2.2412x; 1.4390x over previous
//
#include <hip/hip_runtime.h>
#include <hip/hip_fp16.h>

// SparseEncoder4D: gather-GEMM-scatter sparse conv (1->8->8->1) + dense scatter.
// R7: MFMA restructure of layer 2. R6 counters: FETCH fixed (75 MB) but
// VALU-issue-bound (56% VALUBusy, ~214k VALU cyc/CU of scalar FMAs).
// out[N x 8] = Ghat[N x 648] x W[648 x 8] with Ghat[n][k*8+c] = bit ? h1[idx[n,k]][c] : 0.
// mfma_f32_16x16x32_f16: A-frag lane layout (m=lane&15, k=quad*8+j) means one
// 16 B h1-row gather IS the A-fragment (no transform). Exec-masked gathers:
// only bit-set AND in-slice lanes issue requests -> each active (n,k) gathered
// exactly once across NP=2 L2-resident slice passes. B = w2 f16 in B-layout
// (21.5 KB table, L2-resident), built inside k_h1b. Epilogue: relu * w_out +
// 16-lane shuffle reduce -> outf. part/k_fin deleted.

#define KK 81
#define CH 8
#define NP 2      // idx-range slice passes (1.2 MB table slice stays L2-resident)
#define NS 21     // K-slices of 32: ceil(648/32)
#define KP 84     // padded conv-k slots (4 per slice * 21)
#define TT 4
#define ZZ 32
#define YY 256
#define XX 256

typedef __attribute__((ext_vector_type(8))) _Float16 half8;  // 16 B
typedef __attribute__((ext_vector_type(4))) float f32x4;

// ---------------- layer 1 (feats==ones): h1 fp16 + bitsT + Btab -------------
// bitsT[w][n] bit (k&31) of word w=k>>5 = mask[n][k] (81-bit little-endian).
// Btab[s*64+l] = B-fragment for slice s, lane l: B[32s+8q+j][d=l&15] =
//   w2[4s+q][j][d] (zero for d>=8 or conv-k>=81).
__global__ __launch_bounds__(256) void k_h1b(const float* __restrict__ w1,
                                             const float* __restrict__ w2,
                                             const int* __restrict__ nbr_mask,
                                             half8* __restrict__ h1,
                                             unsigned* __restrict__ bitsT,
                                             half8* __restrict__ Btab, int n_total) {
    __shared__ int lm[256 * 27];  // 27.6 KB
    const int tid = threadIdx.x;
    const int n0 = blockIdx.x * 256;
    const int n = n0 + tid;

    if (blockIdx.x < NS && tid < 64) {   // build Btab (tiny, folded in)
        int s = blockIdx.x, q = tid >> 4, d = tid & 15;
        int kk = 4 * s + q;
        half8 b;
#pragma unroll
        for (int j = 0; j < CH; j++)
            b[j] = (d < CH && kk < KK) ? (_Float16)w2[(kk * CH + j) * CH + d]
                                       : (_Float16)0.f;
        Btab[s * 64 + tid] = b;
    }

    float acc[CH] = {0.f, 0.f, 0.f, 0.f, 0.f, 0.f, 0.f, 0.f};
    unsigned cb[3];
#pragma unroll
    for (int ch = 0; ch < 3; ch++) {
        // stage 27-k chunk, flat coalesced
#pragma unroll
        for (int j = 0; j < 27; j++) {
            int i = tid + j * 256;
            int r = i / 27, c = i - r * 27;
            int srcn = n0 + r; if (srcn >= n_total) srcn = n_total - 1;
            lm[i] = nbr_mask[(long)srcn * KK + ch * 27 + c];
        }
        __syncthreads();
        unsigned cbits = 0;
        const int* row = lm + tid * 27;   // bank stride 27 -> 2-way, free
#pragma unroll
        for (int kk = 0; kk < 27; kk++) {
            int m = row[kk];
            cbits |= (unsigned)(m & 1) << kk;
            float fm = (float)m;
            const float* wp = w1 + (ch * 27 + kk) * CH;  // wave-uniform s_load
#pragma unroll
            for (int c = 0; c < CH; c++) acc[c] += fm * wp[c];
        }
        cb[ch] = cbits;
        __syncthreads();
    }

    if (n < n_total) {
        half8 r;
#pragma unroll
        for (int c = 0; c < CH; c++) r[c] = (_Float16)fmaxf(acc[c], 0.f);
        h1[n] = r;
        bitsT[n]               = cb[0] | (cb[1] << 27);
        bitsT[n_total + n]     = (cb[1] >> 5) | (cb[2] << 22);
        bitsT[2 * n_total + n] = cb[2] >> 10;
    }
}

// ---------------- layer 2 + head: MFMA gather-GEMM --------------------------
// Block = 256 thr = 4 waves; each wave owns 16 rows; block covers 64 rows.
__global__ __launch_bounds__(256) void k_h2m(const half8* __restrict__ h1,
                                             const half8* __restrict__ Btab,
                                             const int* __restrict__ nbr_idx,
                                             const unsigned* __restrict__ bitsT,
                                             const float* __restrict__ w_out,
                                             float* __restrict__ outf,
                                             int n_total, int slice) {
    __shared__ unsigned sidx[64 * KP];   // 21.5 KB masked idx (sentinel = ~0u)
    __shared__ unsigned sbits[3 * 64];   // 768 B
    const int tid = threadIdx.x;
    const int n0 = blockIdx.x * 64;

    if (tid < 192) {
        int w = tid >> 6, r = tid & 63;
        int sn = n0 + r;
        sbits[w * 64 + r] = (sn < n_total) ? bitsT[(long)w * n_total + sn] : 0u;
    }
    __syncthreads();

    // stage masked idx: 64 rows x 84 slots = 5376 = 21*256 (coalesced over c)
#pragma unroll
    for (int j = 0; j < 21; j++) {
        int i = tid + j * 256;
        int r = i / KP, c = i - r * KP;
        unsigned v = 0xFFFFFFFFu;
        int sn = n0 + r;
        if (c < KK && sn < n_total) {
            unsigned bit = (sbits[(c >> 5) * 64 + r] >> (c & 31)) & 1u;
            if (bit) v = (unsigned)nbr_idx[(long)sn * KK + c];
        }
        sidx[i] = v;
    }
    __syncthreads();

    const int lane = tid & 63, wid = tid >> 6;
    const int m = lane & 15, q = lane >> 4;
    const int row_local = wid * 16 + m;
    const unsigned* myidx = sidx + row_local * KP;  // +4s+q per slice; 2-way banks
    const unsigned uslice = (unsigned)slice;

    f32x4 acc = {0.f, 0.f, 0.f, 0.f};
    for (int p = 0; p < NP; p++) {
        unsigned lo = (unsigned)(p * slice);
#pragma unroll 3
        for (int s = 0; s < NS; s++) {
            unsigned ix = myidx[4 * s + q];
            half8 a = {(_Float16)0.f, (_Float16)0.f, (_Float16)0.f, (_Float16)0.f,
                       (_Float16)0.f, (_Float16)0.f, (_Float16)0.f, (_Float16)0.f};
            if (ix - lo < uslice)        // exec-masked: inactive lanes issue no req
                a = h1[ix];              // 16 B gather IS the A-fragment
            half8 b = Btab[s * 64 + lane];  // coalesced, L2-resident 21.5 KB
            acc = __builtin_amdgcn_mfma_f32_16x16x32_f16(a, b, acc, 0, 0, 0);
        }
    }

    // C/D layout: col = lane&15, row = q*4 + reg. Reduce cols (relu * w_out).
    float wo = (m < CH) ? w_out[m] : 0.f;
    float v0 = fmaxf(acc[0], 0.f) * wo, v1 = fmaxf(acc[1], 0.f) * wo;
    float v2 = fmaxf(acc[2], 0.f) * wo, v3 = fmaxf(acc[3], 0.f) * wo;
#pragma unroll
    for (int off = 1; off < 16; off <<= 1) {
        v0 += __shfl_xor(v0, off, 16);
        v1 += __shfl_xor(v1, off, 16);
        v2 += __shfl_xor(v2, off, 16);
        v3 += __shfl_xor(v3, off, 16);
    }
    if (m == 0) {
        int gn = n0 + wid * 16 + q * 4;
        if (gn + 0 < n_total) outf[gn + 0] = v0;
        if (gn + 1 < n_total) outf[gn + 1] = v1;
        if (gn + 2 < n_total) outf[gn + 2] = v2;
        if (gn + 3 < n_total) outf[gn + 3] = v3;
    }
}

// ---------------- deterministic dense scatter -------------------------------
__device__ __forceinline__ int cell_of(const int* coords, const int* batch, int n) {
    int4 c = *(const int4*)(coords + 4 * n);  // (x, y, z, t)
    int b = batch[n];
    return (((b * TT + c.w) * ZZ + c.z) * YY + c.y) * XX + c.x;
}

__global__ __launch_bounds__(256) void k_scat_max(const int* __restrict__ coords,
                                                  const int* __restrict__ batch,
                                                  int* __restrict__ dsti, int n_total) {
    int n = blockIdx.x * blockDim.x + threadIdx.x;
    if (n >= n_total) return;
    atomicMax(dsti + cell_of(coords, batch, n), n + 1);  // winner = max n
}

__global__ __launch_bounds__(256) void k_scat_write(const int* __restrict__ coords,
                                                    const int* __restrict__ batch,
                                                    const float* __restrict__ outf,
                                                    int* dsti, float* dstf, int n_total) {
    int n = blockIdx.x * blockDim.x + threadIdx.x;
    if (n >= n_total) return;
    int cell = cell_of(coords, batch, n);
    if (dsti[cell] == n + 1) dstf[cell] = outf[n];
}

extern "C" void kernel_launch(void* const* d_in, const int* in_sizes, int n_in,
                              void* d_out, int out_size, void* d_ws, size_t ws_size,
                              hipStream_t stream) {
    const float* w1       = (const float*)d_in[1];
    const float* w2       = (const float*)d_in[2];
    const float* w_out    = (const float*)d_in[3];
    const int*   nbr_idx  = (const int*)d_in[4];
    const int*   nbr_mask = (const int*)d_in[5];
    const int*   coords   = (const int*)d_in[6];
    const int*   batch    = (const int*)d_in[7];

    int n_total = in_sizes[0];
    int slice = (n_total + NP - 1) / NP;

    // ws: h1 (N+1 fp16x8, 2.4 MB) | bitsT (3N u32, 1.8 MB) | outf (N f32) | Btab (21.5 KB)
    half8*    h1    = (half8*)d_ws;
    unsigned* bitsT = (unsigned*)((char*)d_ws + (size_t)(n_total + 1) * sizeof(half8));
    float*    outf  = (float*)((char*)bitsT + (size_t)3 * n_total * sizeof(unsigned));
    half8*    Btab  = (half8*)(outf + n_total);
    float*    out   = (float*)d_out;

    hipMemsetAsync(out, 0, (size_t)out_size * sizeof(float), stream);

    int nb = (n_total + 255) / 256;
    k_h1b<<<nb, 256, 0, stream>>>(w1, w2, nbr_mask, h1, bitsT, Btab, n_total);
    int nb2 = (n_total + 63) / 64;
    k_h2m<<<nb2, 256, 0, stream>>>(h1, Btab, nbr_idx, bitsT, w_out, outf, n_total, slice);
    k_scat_max<<<nb, 256, 0, stream>>>(coords, batch, (int*)out, n_total);
    k_scat_write<<<nb, 256, 0, stream>>>(coords, batch, outf, (int*)out, out, n_total);
}